// Round 10
// baseline (571.018 us; speedup 1.0000x reference)
//
#include <hip/hip_runtime.h>
#include <math.h>

typedef unsigned short u16;
typedef unsigned int u32;

namespace {
constexpr int kV = 128000, kD = 512, kNH = 8, kNL = 2, kHID = 1408;
constexpr int kHD = 64, kB = 4, kT = 508, kNLAB = 5, kLBL = 4;
constexpr int kS = 512;                 // T + LBL
constexpr int kNSeq = kNLAB * kB;       // 20
constexpr int kNS = kNSeq * kS;         // 10240 rows
constexpr int kQK = 1024;               // merged q|k row stride
constexpr float kEps = 1e-5f;
constexpr int kNChunk = 4000;           // 32-col partial chunks
constexpr int kPad = 56;                // logits A LDS row stride (bf16)
constexpr int kStr = 72;                // attn LDS row stride (bf16)
constexpr int kPL = 3211264;            // per-layer transposed-weight elems
constexpr int oWQ = 0, oWK = 262144, oWV = 524288, oWO = 786432;
constexpr int oW1 = 1048576, oW3 = 1769472, oW2 = 2490368;
}

typedef __attribute__((ext_vector_type(8))) short bf16x8;
typedef __attribute__((ext_vector_type(4))) float f32x4;

__device__ inline u32 pk2(float lo, float hi) {   // RNE fp32->bf16 pair
  u32 ul = __builtin_bit_cast(u32, lo);
  u32 uh = __builtin_bit_cast(u32, hi);
  ul += 0x7fffu + ((ul >> 16) & 1u);
  uh += 0x7fffu + ((uh >> 16) & 1u);
  return (ul >> 16) | (uh & 0xffff0000u);
}
__device__ inline u16 bf1(float x) {
  u32 u = __builtin_bit_cast(u32, x);
  u += 0x7fffu + ((u >> 16) & 1u);
  return (u16)(u >> 16);
}
__device__ inline float bf2f(u16 u) {
  return __builtin_bit_cast(float, ((u32)u) << 16);
}
__device__ inline void gload16(const void* g, void* l) {
  __builtin_amdgcn_global_load_lds(
      (const __attribute__((address_space(1))) void*)g,
      (__attribute__((address_space(3))) void*)l, 16, 0, 0);
}
// tiled operand index: [row>>7 panel][k>>6 ktile][(kq*2+slot)][row&127][k&7]
__device__ inline size_t tix(int Kt, int row, int k) {
  return ((size_t)(row >> 7) * Kt + (k >> 6)) * 8192 +
         ((((k >> 4) & 3) * 2 + ((k >> 3) & 1)) * 128 + (row & 127)) * 8 + (k & 7);
}

// ---------------- ALL weight transposes in one launch (tiled output) ----------------
__global__ __launch_bounds__(256) void k_wtrans_all(const float* __restrict__ wq,
                                                    const float* __restrict__ wk,
                                                    const float* __restrict__ wv,
                                                    const float* __restrict__ wo,
                                                    const float* __restrict__ w1,
                                                    const float* __restrict__ w3,
                                                    const float* __restrict__ w2,
                                                    u16* __restrict__ wT) {
  int bid = blockIdx.x;
  int l = bid / 3136, r = bid % 3136;
  const float* src; u16* dst; int K, N, gxw, t; float scale = 1.f;
  if (r < 1024) {
    int w = r >> 8; t = r & 255; K = 512; N = 512; gxw = 16;
    src = (w == 0 ? wq : w == 1 ? wk : w == 2 ? wv : wo) + (size_t)l * 262144;
    dst = wT + (size_t)l * kPL + w * 262144;
    if (w == 0) scale = 0.125f;
  } else if (r < 2432) {
    int rr = r - 1024; int w = rr / 704; t = rr - w * 704; K = 512; N = 1408; gxw = 44;
    src = (w ? w3 : w1) + (size_t)l * 720896;
    dst = wT + (size_t)l * kPL + (w ? oW3 : oW1);
  } else {
    t = r - 2432; K = 1408; N = 512; gxw = 16;
    src = w2 + (size_t)l * 720896;
    dst = wT + (size_t)l * kPL + oW2;
  }
  int bn = (t % gxw) * 32, bk = (t / gxw) * 32;
  __shared__ float tb[32][33];
  int tid = threadIdx.x;
  int rr2 = tid >> 3, c4 = (tid & 7) * 4;
  float4 v = *(const float4*)(src + (size_t)(bk + rr2) * N + bn + c4);
  tb[rr2][c4 + 0] = v.x * scale; tb[rr2][c4 + 1] = v.y * scale;
  tb[rr2][c4 + 2] = v.z * scale; tb[rr2][c4 + 3] = v.w * scale;
  __syncthreads();
  uint2 o;
  o.x = pk2(tb[c4 + 0][rr2], tb[c4 + 1][rr2]);
  o.y = pk2(tb[c4 + 2][rr2], tb[c4 + 3][rr2]);
  *(uint2*)&dst[tix(K >> 6, bn + rr2, bk + c4)] = o;
}

// ---------------- fused embedding + first rmsnorm ----------------
__global__ __launch_bounds__(256) void k_embed_rms(const int* __restrict__ input_ids,
                                                   const int* __restrict__ label_ids,
                                                   const float* __restrict__ emb,
                                                   const float* __restrict__ w,
                                                   float* __restrict__ h,
                                                   u16* __restrict__ xn) {
  int row = blockIdx.x;
  int n = row / kS, s = row - n * kS;
  int lab = n / kB, b = n - lab * kB;
  int tok = (s < kT) ? input_ids[b * kT + s] : label_ids[lab * kLBL + (s - kT)];
  int tid = threadIdx.x;
  const float* src = emb + (size_t)tok * kD;
  int i = tid * 2;
  float v0 = src[i], v1 = src[i + 1];
  float ss = v0 * v0 + v1 * v1;
  #pragma unroll
  for (int o = 1; o < 64; o <<= 1) ss += __shfl_xor(ss, o);
  __shared__ float wsum[4];
  int lane = tid & 63, wid = tid >> 6;
  if (lane == 0) wsum[wid] = ss;
  __syncthreads();
  float tot = wsum[0] + wsum[1] + wsum[2] + wsum[3];
  float inv = rsqrtf(tot / (float)kD + kEps);
  *(float2*)&h[(size_t)row * kD + i] = make_float2(v0, v1);
  *(u32*)&xn[tix(8, row, i)] = pk2(v0 * inv * w[i], v1 * inv * w[i + 1]);
}

// ---------------- rmsnorm: fp32 in, bf16 TILED out (K=512 -> Kt=8) ----------------
__global__ __launch_bounds__(256) void k_rmsnorm(const float* __restrict__ x,
                                                 const float* __restrict__ w,
                                                 u16* __restrict__ y) {
  int row = blockIdx.x;
  int tid = threadIdx.x;
  const float* xr = x + (size_t)row * kD;
  int i = tid * 2;
  float v0 = xr[i], v1 = xr[i + 1];
  float ss = v0 * v0 + v1 * v1;
  #pragma unroll
  for (int o = 1; o < 64; o <<= 1) ss += __shfl_xor(ss, o);
  __shared__ float wsum[4];
  int lane = tid & 63, wid = tid >> 6;
  if (lane == 0) wsum[wid] = ss;
  __syncthreads();
  float tot = wsum[0] + wsum[1] + wsum[2] + wsum[3];
  float inv = rsqrtf(tot / (float)kD + kEps);
  *(u32*)&y[tix(8, row, i)] = pk2(v0 * inv * w[i], v1 * inv * w[i + 1]);
}

// ---------------- QKV GEMM (tiled A,B): q,k->qk (RoPE fused), v->vT transposed ----------------
__global__ __launch_bounds__(256) void k_gemm_qkv(const u16* __restrict__ A,
                                                  const u16* __restrict__ Bt,
                                                  u16* __restrict__ qk,
                                                  u16* __restrict__ vT) {
  __shared__ u16 As[8192];
  __shared__ u16 Bs[8192];
  int wg = (blockIdx.x & 7) * 120 + (blockIdx.x >> 3);
  int by = wg / 12, bx = wg - by * 12;
  int row0 = by * 128, col0 = bx * 128;
  int tid = threadIdx.x;
  int wave = tid >> 6, lane = tid & 63;
  int wm = wave >> 1, wn = wave & 1;
  int l15 = lane & 15, l16 = lane >> 4;
  f32x4 acc[4][4];
  #pragma unroll
  for (int i = 0; i < 4; i++)
    #pragma unroll
    for (int j = 0; j < 4; j++) acc[i][j] = (f32x4){0.f, 0.f, 0.f, 0.f};

  for (int kt = 0; kt < 8; kt++) {
    const u16* Ab = A  + ((size_t)(row0 >> 7) * 8 + kt) * 8192;
    const u16* Bb = Bt + ((size_t)(col0 >> 7) * 8 + kt) * 8192;
    #pragma unroll
    for (int i = 0; i < 4; i++) {
      int off = ((wave * 2 + (i >> 1)) * 128 + (i & 1) * 64) * 8;
      gload16(Ab + off + (size_t)lane * 8, (char*)As + off * 2);
      gload16(Bb + off + (size_t)lane * 8, (char*)Bs + off * 2);
    }
    __syncthreads();
    #pragma unroll
    for (int h = 0; h < 2; h++) {
      bf16x8 af[4], bfr[4];
      #pragma unroll
      for (int mf = 0; mf < 4; mf++)
        af[mf] = *(const bf16x8*)&As[((h * 4 + l16) * 128 + wm * 64 + mf * 16 + l15) * 8];
      #pragma unroll
      for (int nf = 0; nf < 4; nf++)
        bfr[nf] = *(const bf16x8*)&Bs[((h * 4 + l16) * 128 + wn * 64 + nf * 16 + l15) * 8];
      #pragma unroll
      for (int mf = 0; mf < 4; mf++)
        #pragma unroll
        for (int nf = 0; nf < 4; nf++)
          acc[mf][nf] = __builtin_amdgcn_mfma_f32_16x16x32_bf16(af[mf], bfr[nf], acc[mf][nf], 0, 0, 0);
    }
    __syncthreads();
  }

  if (bx < 8) {      // q or k: apply RoPE to pairs (d, d+32), d = nf*16+l15, nf in {0,1}
    #pragma unroll
    for (int nf = 0; nf < 2; nf++) {
      int d = nf * 16 + l15;
      float fr = __expf(-0.2878231366242558f * (float)d);    // 10000^(-d/32)
      #pragma unroll
      for (int mf = 0; mf < 4; mf++)
        #pragma unroll
        for (int r = 0; r < 4; r++) {
          int row = row0 + wm * 64 + mf * 16 + l16 * 4 + r;
          int s = row & (kS - 1);
          float sn, cs;
          __sincosf((float)s * fr, &sn, &cs);
          float x1 = acc[mf][nf][r], x2 = acc[mf][nf + 2][r];
          size_t base = (size_t)row * kQK + col0 + wn * 64 + nf * 16 + l15;
          qk[base]      = bf1(x1 * cs - x2 * sn);
          qk[base + 32] = bf1(x1 * sn + x2 * cs);
        }
    }
  } else {           // v: store transposed per head: vT[(n*8+h)*64 + d][s]
    int n = row0 >> 9;
    #pragma unroll
    for (int mf = 0; mf < 4; mf++) {
      int s0 = (row0 & (kS - 1)) + wm * 64 + mf * 16 + l16 * 4;
      #pragma unroll
      for (int nf = 0; nf < 4; nf++) {
        int v = (bx - 8) * 128 + wn * 64 + nf * 16 + l15;   // 0..511
        int hh = v >> 6, d = v & 63;
        uint2 ow;
        ow.x = pk2(acc[mf][nf][0], acc[mf][nf][1]);
        ow.y = pk2(acc[mf][nf][2], acc[mf][nf][3]);
        *(uint2*)&vT[(size_t)((n * kNH + hh) * kHD + d) * kS + s0] = ow;
      }
    }
  }
}

// ---------------- 128x64-tile GEMM (tiled A,B), C fp32 += A@B ----------------
__global__ __launch_bounds__(256) void k_gemm_n64(const u16* __restrict__ A,
                                                  const u16* __restrict__ Bt,
                                                  float* __restrict__ C,
                                                  int Kt, int N) {
  __shared__ u16 As[8192];
  __shared__ u16 Bs[4096];
  int nwg = gridDim.x;
  int wg = (blockIdx.x & 7) * (nwg >> 3) + (blockIdx.x >> 3);
  int by = wg >> 3, bx = wg & 7;
  int row0 = by * 128, col0 = bx * 64;
  int p = col0 >> 7, half = (col0 >> 6) & 1;
  int tid = threadIdx.x;
  int wave = tid >> 6, lane = tid & 63;
  int l15 = lane & 15, l16 = lane >> 4;
  f32x4 acc[2][4];
  #pragma unroll
  for (int i = 0; i < 2; i++)
    #pragma unroll
    for (int j = 0; j < 4; j++) acc[i][j] = (f32x4){0.f, 0.f, 0.f, 0.f};

  for (int kt = 0; kt < Kt; kt++) {
    const u16* Ab = A  + ((size_t)(row0 >> 7) * Kt + kt) * 8192;
    const u16* Bb = Bt + ((size_t)p * Kt + kt) * 8192;
    #pragma unroll
    for (int i = 0; i < 4; i++) {
      int off = ((wave * 2 + (i >> 1)) * 128 + (i & 1) * 64) * 8;
      gload16(Ab + off + (size_t)lane * 8, (char*)As + off * 2);
    }
    #pragma unroll
    for (int sl = 0; sl < 2; sl++) {
      int ch = wave * 2 + sl;
      gload16(Bb + (ch * 128 + half * 64) * 8 + (size_t)lane * 8,
              (char*)Bs + (ch * 64) * 16);
    }
    __syncthreads();
    #pragma unroll
    for (int h = 0; h < 2; h++) {
      bf16x8 af[2], bfr[4];
      #pragma unroll
      for (int mf = 0; mf < 2; mf++)
        af[mf] = *(const bf16x8*)&As[((h * 4 + l16) * 128 + wave * 32 + mf * 16 + l15) * 8];
      #pragma unroll
      for (int nf = 0; nf < 4; nf++)
        bfr[nf] = *(const bf16x8*)&Bs[((h * 4 + l16) * 64 + nf * 16 + l15) * 8];
      #pragma unroll
      for (int mf = 0; mf < 2; mf++)
        #pragma unroll
        for (int nf = 0; nf < 4; nf++)
          acc[mf][nf] = __builtin_amdgcn_mfma_f32_16x16x32_bf16(af[mf], bfr[nf], acc[mf][nf], 0, 0, 0);
    }
    __syncthreads();
  }
  #pragma unroll
  for (int mf = 0; mf < 2; mf++)
    #pragma unroll
    for (int nf = 0; nf < 4; nf++)
      #pragma unroll
      for (int r = 0; r < 4; r++) {
        int row = row0 + wave * 32 + mf * 16 + l16 * 4 + r;
        int col = col0 + nf * 16 + l15;
        C[(size_t)row * N + col] += acc[mf][nf][r];
      }
}

// ---------------- FFN dual GEMM (tiled A,B1,B3): act(tiled,Kt=22) = silu(A@W1)*(A@W3) ----------------
__global__ __launch_bounds__(256) void k_ffn13_bf16(const u16* __restrict__ A,
                                                    const u16* __restrict__ W1t,
                                                    const u16* __restrict__ W3t,
                                                    u16* __restrict__ act) {
  __shared__ u16 As[8192];
  __shared__ u16 B1[8192];
  __shared__ u16 B2[8192];
  int wg = (blockIdx.x & 7) * 110 + (blockIdx.x >> 3);
  int by = wg / 11, bx = wg - by * 11;
  int row0 = by * 128, col0 = bx * 128;
  int tid = threadIdx.x;
  int wave = tid >> 6, lane = tid & 63;
  int wm = wave >> 1, wn = wave & 1;
  int l15 = lane & 15, l16 = lane >> 4;
  f32x4 acc1[4][4], acc2[4][4];
  #pragma unroll
  for (int i = 0; i < 4; i++)
    #pragma unroll
    for (int j = 0; j < 4; j++) {
      acc1[i][j] = (f32x4){0.f, 0.f, 0.f, 0.f};
      acc2[i][j] = (f32x4){0.f, 0.f, 0.f, 0.f};
    }

  for (int kt = 0; kt < 8; kt++) {
    const u16* Ab  = A   + ((size_t)(row0 >> 7) * 8 + kt) * 8192;
    const u16* B1b = W1t + ((size_t)(col0 >> 7) * 8 + kt) * 8192;
    const u16* B3b = W3t + ((size_t)(col0 >> 7) * 8 + kt) * 8192;
    #pragma unroll
    for (int i = 0; i < 4; i++) {
      int off = ((wave * 2 + (i >> 1)) * 128 + (i & 1) * 64) * 8;
      gload16(Ab  + off + (size_t)lane * 8, (char*)As + off * 2);
      gload16(B1b + off + (size_t)lane * 8, (char*)B1 + off * 2);
      gload16(B3b + off + (size_t)lane * 8, (char*)B2 + off * 2);
    }
    __syncthreads();
    #pragma unroll
    for (int h = 0; h < 2; h++) {
      bf16x8 af[4], b1f[4], b2f[4];
      #pragma unroll
      for (int mf = 0; mf < 4; mf++)
        af[mf] = *(const bf16x8*)&As[((h * 4 + l16) * 128 + wm * 64 + mf * 16 + l15) * 8];
      #pragma unroll
      for (int nf = 0; nf < 4; nf++) {
        b1f[nf] = *(const bf16x8*)&B1[((h * 4 + l16) * 128 + wn * 64 + nf * 16 + l15) * 8];
        b2f[nf] = *(const bf16x8*)&B2[((h * 4 + l16) * 128 + wn * 64 + nf * 16 + l15) * 8];
      }
      #pragma unroll
      for (int mf = 0; mf < 4; mf++)
        #pragma unroll
        for (int nf = 0; nf < 4; nf++) {
          acc1[mf][nf] = __builtin_amdgcn_mfma_f32_16x16x32_bf16(af[mf], b1f[nf], acc1[mf][nf], 0, 0, 0);
          acc2[mf][nf] = __builtin_amdgcn_mfma_f32_16x16x32_bf16(af[mf], b2f[nf], acc2[mf][nf], 0, 0, 0);
        }
    }
    __syncthreads();
  }
  #pragma unroll
  for (int mf = 0; mf < 4; mf++)
    #pragma unroll
    for (int nf = 0; nf < 4; nf++)
      #pragma unroll
      for (int r = 0; r < 4; r++) {
        int row = row0 + wm * 64 + mf * 16 + l16 * 4 + r;
        int col = col0 + wn * 64 + nf * 16 + l15;
        float aa = acc1[mf][nf][r];
        float sg = 1.f / (1.f + __expf(-aa));
        act[tix(22, row, col)] = bf1(aa * sg * acc2[mf][nf][r]);
      }
}

// ---------------- MFMA flash attention, QBLK=128 (4 waves x 32 q-rows) ----------------
__global__ __launch_bounds__(256) void k_attn_mfma(const u16* __restrict__ qk,
                                                   const u16* __restrict__ vT,
                                                   u16* __restrict__ o) {
  int qb = blockIdx.x;                 // 0..3
  int nh = blockIdx.y;
  int hh = nh & (kNH - 1), n = nh >> 3;
  int tid = threadIdx.x;
  int wq = tid >> 6, lane = tid & 63;
  int l15 = lane & 15, l16 = lane >> 4;
  __shared__ u16 Ks[64 * kStr];        // [kv][hd]
  __shared__ u16 Vt[64 * kStr];        // [hd][kv]
  __shared__ u16 Ps[4][32 * kStr];     // per-wave P [q 0..31][kv]
  int qbase = qb * 128 + wq * 32;

  bf16x8 qf[2][2];
  #pragma unroll
  for (int g = 0; g < 2; g++) {
    const u16* qg = qk + (size_t)(n * kS + qbase + g * 16 + l15) * kQK + hh * kHD;
    qf[g][0] = *(const bf16x8*)(qg + l16 * 8);
    qf[g][1] = *(const bf16x8*)(qg + 32 + l16 * 8);
  }

  f32x4 oacc[2][4];
  #pragma unroll
  for (int g = 0; g < 2; g++)
    #pragma unroll
    for (int i = 0; i < 4; i++) oacc[g][i] = (f32x4){0.f, 0.f, 0.f, 0.f};
  float m_run[2] = {-1e30f, -1e30f}, l_run[2] = {0.f, 0.f};

  int skv = tid & 63, sd0 = (tid >> 6) * 16;
  const u16* vTh = vT + (size_t)((n * kNH + hh) * kHD) * kS;
  int ntile = 2 * qb + 2;

  for (int jt = 0; jt < ntile; jt++) {
    int j0 = jt * 64;
    __syncthreads();
    {
      size_t gb = (size_t)(n * kS + j0 + skv) * kQK + 512 + hh * kHD + sd0;
      const u16* kg = qk + gb;
      *(uint4*)&Ks[skv * kStr + sd0]     = *(const uint4*)kg;
      *(uint4*)&Ks[skv * kStr + sd0 + 8] = *(const uint4*)(kg + 8);
      const u16* vg = vTh + (size_t)skv * kS + j0 + sd0;
      *(uint4*)&Vt[skv * kStr + sd0]     = *(const uint4*)vg;
      *(uint4*)&Vt[skv * kStr + sd0 + 8] = *(const uint4*)(vg + 8);
    }
    __syncthreads();

    #pragma unroll
    for (int g = 0; g < 2; g++) {
      int qrow = qbase + g * 16 + l15;
      f32x4 st[4];
      #pragma unroll
      for (int kt = 0; kt < 4; kt++) {
        bf16x8 ka0 = *(const bf16x8*)&Ks[(kt * 16 + l15) * kStr + l16 * 8];
        bf16x8 ka1 = *(const bf16x8*)&Ks[(kt * 16 + l15) * kStr + 32 + l16 * 8];
        f32x4 c = (f32x4){0.f, 0.f, 0.f, 0.f};
        c = __builtin_amdgcn_mfma_f32_16x16x32_bf16(ka0, qf[g][0], c, 0, 0, 0);
        c = __builtin_amdgcn_mfma_f32_16x16x32_bf16(ka1, qf[g][1], c, 0, 0, 0);
        st[kt] = c;
      }
      float mx = m_run[g];
      #pragma unroll
      for (int kt = 0; kt < 4; kt++)
        #pragma unroll
        for (int r = 0; r < 4; r++) {
          int kvg = j0 + kt * 16 + l16 * 4 + r;
          if (kvg > qrow) st[kt][r] = -1e30f;
          mx = fmaxf(mx, st[kt][r]);
        }
      mx = fmaxf(mx, __shfl_xor(mx, 16));
      mx = fmaxf(mx, __shfl_xor(mx, 32));
      float sc = __expf(m_run[g] - mx);
      float p[4][4];
      float rs = 0.f;
      #pragma unroll
      for (int kt = 0; kt < 4; kt++)
        #pragma unroll
        for (int r = 0; r < 4; r++) { p[kt][r] = __expf(st[kt][r] - mx); rs += p[kt][r]; }
      rs += __shfl_xor(rs, 16);
      rs += __shfl_xor(rs, 32);
      l_run[g] = l_run[g] * sc + rs;
      m_run[g] = mx;
      #pragma unroll
      for (int dt = 0; dt < 4; dt++)
        #pragma unroll
        for (int r = 0; r < 4; r++) oacc[g][dt][r] *= sc;

      #pragma unroll
      for (int kt = 0; kt < 4; kt++) {
        uint2 w2;
        w2.x = pk2(p[kt][0], p[kt][1]);
        w2.y = pk2(p[kt][2], p[kt][3]);
        *(uint2*)&Ps[wq][(g * 16 + l15) * kStr + kt * 16 + l16 * 4] = w2;
      }
    }
    asm volatile("s_waitcnt lgkmcnt(0)" ::: "memory");
    __builtin_amdgcn_sched_barrier(0);

    bf16x8 pf[2][2];
    #pragma unroll
    for (int g = 0; g < 2; g++) {
      pf[g][0] = *(const bf16x8*)&Ps[wq][(g * 16 + l15) * kStr + l16 * 8];
      pf[g][1] = *(const bf16x8*)&Ps[wq][(g * 16 + l15) * kStr + 32 + l16 * 8];
    }
    #pragma unroll
    for (int dt = 0; dt < 4; dt++) {
      bf16x8 va0 = *(const bf16x8*)&Vt[(dt * 16 + l15) * kStr + l16 * 8];
      bf16x8 va1 = *(const bf16x8*)&Vt[(dt * 16 + l15) * kStr + 32 + l16 * 8];
      #pragma unroll
      for (int g = 0; g < 2; g++) {
        oacc[g][dt] = __builtin_amdgcn_mfma_f32_16x16x32_bf16(va0, pf[g][0], oacc[g][dt], 0, 0, 0);
        oacc[g][dt] = __builtin_amdgcn_mfma_f32_16x16x32_bf16(va1, pf[g][1], oacc[g][dt], 0, 0, 0);
      }
    }
  }

  // tiled store: k = hh*64 + dt*16 + l16*4 -> panel (row>>7), ktile hh
  #pragma unroll
  for (int g = 0; g < 2; g++) {
    float inv = 1.f / l_run[g];
    int rowIdx = n * kS + qbase + g * 16 + l15;
    #pragma unroll
    for (int dt = 0; dt < 4; dt++) {
      uint2 ow;
      ow.x = pk2(oacc[g][dt][0] * inv, oacc[g][dt][1] * inv);
      ow.y = pk2(oacc[g][dt][2] * inv, oacc[g][dt][3] * inv);
      size_t base = ((size_t)(rowIdx >> 7) * 8 + hh) * 8192 +
                    (size_t)(((dt * 2 + ((l16 >> 1) & 1)) * 128 + (rowIdx & 127)) * 8 + (l16 & 1) * 4);
      *(uint2*)&o[base] = ow;
    }
  }
}

// ---------------- final rmsnorm + gather: only the 80 scoring rows ----------------
__global__ __launch_bounds__(256) void k_rms_gather(const float* __restrict__ x,
                                                    const float* __restrict__ w,
                                                    u16* __restrict__ hs) {
  int r = blockIdx.x;                       // 0..79
  int n = r >> 2, li = r & 3;
  int row = n * kS + (kT - 1 + li);
  int tid = threadIdx.x;
  const float* xr = x + (size_t)row * kD;
  int i = tid * 2;
  float v0 = xr[i], v1 = xr[i + 1];
  float ss = v0 * v0 + v1 * v1;
  #pragma unroll
  for (int o = 1; o < 64; o <<= 1) ss += __shfl_xor(ss, o);
  __shared__ float wsum[4];
  int lane = tid & 63, wid = tid >> 6;
  if (lane == 0) wsum[wid] = ss;
  __syncthreads();
  float tot = wsum[0] + wsum[1] + wsum[2] + wsum[3];
  float inv = rsqrtf(tot / (float)kD + kEps);
  *(u32*)&hs[(size_t)r * kD + i] = pk2(v0 * inv * w[i], v1 * inv * w[i + 1]);
}

// ---------------- logits partials via MFMA: 128 cols/block, 1000 blocks ----------------
__global__ __launch_bounds__(256) void k_logits_mfma(const u16* __restrict__ hs,
                                                     const float* __restrict__ lm,
                                                     float* __restrict__ part) {
  __shared__ u16 As[80 * kPad];
  __shared__ u16 Bs[4 * 128 * 8];
  int tid = threadIdx.x;
  int wave = tid >> 6, lane = tid & 63;
  int l15 = lane & 15, l16 = lane >> 4;
  int col0 = blockIdx.x * 128;
  f32x4 acc[5][2];
  #pragma unroll
  for (int i = 0; i < 5; i++)
    #pragma unroll
    for (int j = 0; j < 2; j++) acc[i][j] = (f32x4){0.f, 0.f, 0.f, 0.f};

  int arow = tid >> 1, ahalf = tid & 1;
  int bkp = tid >> 4, bf4 = tid & 15;     // k-pair 0..15, col-quad 0..15
  int slot = bkp >> 2, ksub = (2 * bkp) & 7;

  for (int k0 = 0; k0 < kD; k0 += 32) {
    if (tid < 160) {
      const u16* ag = hs + (size_t)arow * kD + k0 + ahalf * 16;
      *(uint4*)&As[arow * kPad + ahalf * 16]     = *(const uint4*)ag;
      *(uint4*)&As[arow * kPad + ahalf * 16 + 8] = *(const uint4*)(ag + 8);
    }
    #pragma unroll
    for (int t = 0; t < 2; t++) {
      int colq = bf4 + 16 * t;              // 0..31
      const float* bg = lm + (size_t)(k0 + 2 * bkp) * kV + col0 + colq * 4;
      float4 lo = *(const float4*)bg;
      float4 hi = *(const float4*)(bg + kV);
      *(u32*)&Bs[(slot * 128 + colq * 4 + 0) * 8 + ksub] = pk2(lo.x, hi.x);
      *(u32*)&Bs[(slot * 128 + colq * 4 + 1) * 8 + ksub] = pk2(lo.y, hi.y);
      *(u32*)&Bs[(slot * 128 + colq * 4 + 2) * 8 + ksub] = pk2(lo.z, hi.z);
      *(u32*)&Bs[(slot * 128 + colq * 4 + 3) * 8 + ksub] = pk2(lo.w, hi.w);
    }
    __syncthreads();
    bf16x8 af[5], bfr[2];
    #pragma unroll
    for (int mf = 0; mf < 5; mf++)
      af[mf] = *(const bf16x8*)&As[(mf * 16 + l15) * kPad + l16 * 8];
    #pragma unroll
    for (int nf = 0; nf < 2; nf++)
      bfr[nf] = *(const bf16x8*)&Bs[(l16 * 128 + wave * 32 + nf * 16 + l15) * 8];
    #pragma unroll
    for (int mf = 0; mf < 5; mf++)
      #pragma unroll
      for (int nf = 0; nf < 2; nf++)
        acc[mf][nf] = __builtin_amdgcn_mfma_f32_16x16x32_bf16(af[mf], bfr[nf], acc[mf][nf], 0, 0, 0);
    __syncthreads();
  }

  int chunk = blockIdx.x * 4 + wave;        // 4000 chunks of 32 cols
  #pragma unroll
  for (int mf = 0; mf < 5; mf++)
    #pragma unroll
    for (int r = 0; r < 4; r++) {
      float mx = fmaxf(acc[mf][0][r], acc[mf][1][r]);
      #pragma unroll
      for (int off = 1; off < 16; off <<= 1) mx = fmaxf(mx, __shfl_xor(mx, off));
      float se = expf(acc[mf][0][r] - mx) + expf(acc[mf][1][r] - mx);
      #pragma unroll
      for (int off = 1; off < 16; off <<= 1) se += __shfl_xor(se, off);
      if (l15 == 0) {
        int row = mf * 16 + l16 * 4 + r;
        size_t pi = ((size_t)row * kNChunk + chunk) * 2;
        part[pi] = mx; part[pi + 1] = se;
      }
    }
}

// ---------------- final: label logits + logsumexp combine + output ----------------
__global__ __launch_bounds__(64) void k_final(const float* __restrict__ part,
                                              const u16* __restrict__ hs,
                                              const float* __restrict__ lm,
                                              const int* __restrict__ label_ids,
                                              float* __restrict__ out) {
  int n = blockIdx.x;
  int lab = n / kB, b = n - lab * kB;
  int lane = threadIdx.x;
  float res = 0.f;
  for (int li = 0; li < kLBL; li++) {
    int r = n * kLBL + li;
    int tok = label_ids[lab * kLBL + li];
    float dv = 0.f;
    for (int d2 = lane; d2 < kD; d2 += 64)
      dv += bf2f(hs[(size_t)r * kD + d2]) * lm[(size_t)d2 * kV + tok];
    #pragma unroll
    for (int o2 = 1; o2 < 64; o2 <<= 1) dv += __shfl_xor(dv, o2);
    const float* pr = part + (size_t)r * kNChunk * 2;
    float mx = -1e30f;
    for (int c = lane; c < kNChunk; c += 64) mx = fmaxf(mx, pr[c * 2]);
    #pragma unroll
    for (int o2 = 1; o2 < 64; o2 <<= 1) mx = fmaxf(mx, __shfl_xor(mx, o2));
    float sum = 0.f;
    for (int c = lane; c < kNChunk; c += 64) sum += pr[c * 2 + 1] * expf(pr[c * 2] - mx);
    #pragma unroll
    for (int o2 = 1; o2 < 64; o2 <<= 1) sum += __shfl_xor(sum, o2);
    res += dv - (mx + logf(sum));
  }
  if (lane == 0) out[b * kNLAB + lab] = res;
}

extern "C" void kernel_launch(void* const* d_in, const int* in_sizes, int n_in,
                              void* d_out, int out_size, void* d_ws, size_t ws_size,
                              hipStream_t stream) {
  const int*   input_ids    = (const int*)d_in[0];
  const int*   label_ids    = (const int*)d_in[1];
  const float* emb          = (const float*)d_in[2];
  const float* wq           = (const float*)d_in[3];
  const float* wk           = (const float*)d_in[4];
  const float* wv           = (const float*)d_in[5];
  const float* wo           = (const float*)d_in[6];
  const float* w1           = (const float*)d_in[7];
  const float* w2           = (const float*)d_in[8];
  const float* w3           = (const float*)d_in[9];
  const float* attn_norm_w  = (const float*)d_in[10];
  const float* ffn_norm_w   = (const float*)d_in[11];
  const float* final_norm_w = (const float*)d_in[12];
  const float* lm_head      = (const float*)d_in[13];
  float* out = (float*)d_out;

  char* ws = (char*)d_ws;
  float* h    = (float*)(ws);                  // 20,971,520 B fp32
  u16*   xn   = (u16*)(ws + 20971520);         // 10,485,760 bf16 (tiled Kt=8)
  u16*   qk   = (u16*)(ws + 31457280);         // 20,971,520 bf16 [kNS][1024] plain
  u16*   vT   = (u16*)(ws + 52428800);         // 10,485,760 bf16 [20*8*64][512]
  u16*   big  = (u16*)(ws + 62914560);         // 28,835,840 (attn-out tiled Kt=8 / ffn act tiled Kt=22)
  u16*   hsb  = (u16*)(ws + 91750400);         // 81,920 plain [80][512]
  float* part = (float*)(ws + 91832320);       // 2,560,000
  u16*   wT   = (u16*)(ws + 94392320);         // 12,845,056 (tiled)

  k_wtrans_all<<<2 * 3136, 256, 0, stream>>>(wq, wk, wv, wo, w1, w3, w2, wT);
  k_embed_rms<<<kNS, 256, 0, stream>>>(input_ids, label_ids, emb, attn_norm_w, h, xn);

  for (int l = 0; l < kNL; l++) {
    u16* base = wT + (size_t)l * kPL;
    if (l > 0)
      k_rmsnorm<<<kNS, 256, 0, stream>>>(h, attn_norm_w + (size_t)l * kD, xn);
    k_gemm_qkv<<<960, 256, 0, stream>>>(xn, base + oWQ, qk, vT);
    dim3 gattn(kS / 128, kNSeq * kNH);
    k_attn_mfma<<<gattn, 256, 0, stream>>>(qk, vT, big);
    k_gemm_n64<<<640, 256, 0, stream>>>(big, base + oWO, h, 8, kD);
    k_rmsnorm<<<kNS, 256, 0, stream>>>(h, ffn_norm_w + (size_t)l * kD, xn);
    k_ffn13_bf16<<<880, 256, 0, stream>>>(xn, base + oW1, base + oW3, big);
    k_gemm_n64<<<640, 256, 0, stream>>>(big, base + oW2, h, 22, kD);
  }

  k_rms_gather<<<kNSeq * kLBL, 256, 0, stream>>>(h, final_norm_w, hsb);
  k_logits_mfma<<<kV / 128, 256, 0, stream>>>(hsb, lm_head, part);
  k_final<<<kNSeq, 64, 0, stream>>>(part, hsb, lm_head, label_ids, out);
}

// Round 11
// 519.753 us; speedup vs baseline: 1.0986x; 1.0986x over previous
//
#include <hip/hip_runtime.h>
#include <math.h>

typedef unsigned short u16;
typedef unsigned int u32;

namespace {
constexpr int kV = 128000, kD = 512, kNH = 8, kNL = 2, kHID = 1408;
constexpr int kHD = 64, kB = 4, kT = 508, kNLAB = 5, kLBL = 4;
constexpr int kS = 512;                 // T + LBL
constexpr int kNSeq = kNLAB * kB;       // 20
constexpr int kNS = kNSeq * kS;         // 10240 rows
constexpr int kQK = 1024;               // merged q|k row stride
constexpr float kEps = 1e-5f;
constexpr int kNChunk = 2000;           // 64-col partial chunks
constexpr int kPad = 56;                // logits A LDS row stride (bf16)
constexpr int kStr = 72;                // attn LDS row stride (bf16)
constexpr int kPL = 3211264;            // per-layer transposed-weight elems
constexpr int oWQ = 0, oWK = 262144, oWV = 524288, oWO = 786432;
constexpr int oW1 = 1048576, oW3 = 1769472, oW2 = 2490368;
}

typedef __attribute__((ext_vector_type(8))) short bf16x8;
typedef __attribute__((ext_vector_type(4))) float f32x4;

__device__ inline u32 pk2(float lo, float hi) {   // RNE fp32->bf16 pair
  u32 ul = __builtin_bit_cast(u32, lo);
  u32 uh = __builtin_bit_cast(u32, hi);
  ul += 0x7fffu + ((ul >> 16) & 1u);
  uh += 0x7fffu + ((uh >> 16) & 1u);
  return (ul >> 16) | (uh & 0xffff0000u);
}
__device__ inline u16 bf1(float x) {
  u32 u = __builtin_bit_cast(u32, x);
  u += 0x7fffu + ((u >> 16) & 1u);
  return (u16)(u >> 16);
}
__device__ inline float bf2f(u16 u) {
  return __builtin_bit_cast(float, ((u32)u) << 16);
}
__device__ inline void gload16(const void* g, void* l) {
  __builtin_amdgcn_global_load_lds(
      (const __attribute__((address_space(1))) void*)g,
      (__attribute__((address_space(3))) void*)l, 16, 0, 0);
}
// tiled operand index: [row>>7 panel][k>>6 ktile][(kq*2+slot)][row&127][k&7]
__device__ inline size_t tix(int Kt, int row, int k) {
  return ((size_t)(row >> 7) * Kt + (k >> 6)) * 8192 +
         ((((k >> 4) & 3) * 2 + ((k >> 3) & 1)) * 128 + (row & 127)) * 8 + (k & 7);
}

// ---------------- ALL weight transposes in one launch (tiled output) ----------------
__global__ __launch_bounds__(256) void k_wtrans_all(const float* __restrict__ wq,
                                                    const float* __restrict__ wk,
                                                    const float* __restrict__ wv,
                                                    const float* __restrict__ wo,
                                                    const float* __restrict__ w1,
                                                    const float* __restrict__ w3,
                                                    const float* __restrict__ w2,
                                                    u16* __restrict__ wT) {
  int bid = blockIdx.x;
  int l = bid / 3136, r = bid % 3136;
  const float* src; u16* dst; int K, N, gxw, t; float scale = 1.f;
  if (r < 1024) {
    int w = r >> 8; t = r & 255; K = 512; N = 512; gxw = 16;
    src = (w == 0 ? wq : w == 1 ? wk : w == 2 ? wv : wo) + (size_t)l * 262144;
    dst = wT + (size_t)l * kPL + w * 262144;
    if (w == 0) scale = 0.125f;
  } else if (r < 2432) {
    int rr = r - 1024; int w = rr / 704; t = rr - w * 704; K = 512; N = 1408; gxw = 44;
    src = (w ? w3 : w1) + (size_t)l * 720896;
    dst = wT + (size_t)l * kPL + (w ? oW3 : oW1);
  } else {
    t = r - 2432; K = 1408; N = 512; gxw = 16;
    src = w2 + (size_t)l * 720896;
    dst = wT + (size_t)l * kPL + oW2;
  }
  int bn = (t % gxw) * 32, bk = (t / gxw) * 32;
  __shared__ float tb[32][33];
  int tid = threadIdx.x;
  int rr2 = tid >> 3, c4 = (tid & 7) * 4;
  float4 v = *(const float4*)(src + (size_t)(bk + rr2) * N + bn + c4);
  tb[rr2][c4 + 0] = v.x * scale; tb[rr2][c4 + 1] = v.y * scale;
  tb[rr2][c4 + 2] = v.z * scale; tb[rr2][c4 + 3] = v.w * scale;
  __syncthreads();
  uint2 o;
  o.x = pk2(tb[c4 + 0][rr2], tb[c4 + 1][rr2]);
  o.y = pk2(tb[c4 + 2][rr2], tb[c4 + 3][rr2]);
  *(uint2*)&dst[tix(K >> 6, bn + rr2, bk + c4)] = o;
}

// ---------------- fused embedding + first rmsnorm ----------------
__global__ __launch_bounds__(256) void k_embed_rms(const int* __restrict__ input_ids,
                                                   const int* __restrict__ label_ids,
                                                   const float* __restrict__ emb,
                                                   const float* __restrict__ w,
                                                   float* __restrict__ h,
                                                   u16* __restrict__ xn) {
  int row = blockIdx.x;
  int n = row / kS, s = row - n * kS;
  int lab = n / kB, b = n - lab * kB;
  int tok = (s < kT) ? input_ids[b * kT + s] : label_ids[lab * kLBL + (s - kT)];
  int tid = threadIdx.x;
  const float* src = emb + (size_t)tok * kD;
  int i = tid * 2;
  float v0 = src[i], v1 = src[i + 1];
  float ss = v0 * v0 + v1 * v1;
  #pragma unroll
  for (int o = 1; o < 64; o <<= 1) ss += __shfl_xor(ss, o);
  __shared__ float wsum[4];
  int lane = tid & 63, wid = tid >> 6;
  if (lane == 0) wsum[wid] = ss;
  __syncthreads();
  float tot = wsum[0] + wsum[1] + wsum[2] + wsum[3];
  float inv = rsqrtf(tot / (float)kD + kEps);
  *(float2*)&h[(size_t)row * kD + i] = make_float2(v0, v1);
  *(u32*)&xn[tix(8, row, i)] = pk2(v0 * inv * w[i], v1 * inv * w[i + 1]);
}

// ---------------- rmsnorm: fp32 in, bf16 TILED out (K=512 -> Kt=8) ----------------
__global__ __launch_bounds__(256) void k_rmsnorm(const float* __restrict__ x,
                                                 const float* __restrict__ w,
                                                 u16* __restrict__ y) {
  int row = blockIdx.x;
  int tid = threadIdx.x;
  const float* xr = x + (size_t)row * kD;
  int i = tid * 2;
  float v0 = xr[i], v1 = xr[i + 1];
  float ss = v0 * v0 + v1 * v1;
  #pragma unroll
  for (int o = 1; o < 64; o <<= 1) ss += __shfl_xor(ss, o);
  __shared__ float wsum[4];
  int lane = tid & 63, wid = tid >> 6;
  if (lane == 0) wsum[wid] = ss;
  __syncthreads();
  float tot = wsum[0] + wsum[1] + wsum[2] + wsum[3];
  float inv = rsqrtf(tot / (float)kD + kEps);
  *(u32*)&y[tix(8, row, i)] = pk2(v0 * inv * w[i], v1 * inv * w[i + 1]);
}

// ---------------- QKV GEMM (tiled A,B): q,k->qk (RoPE fused), v->vT transposed ----------------
__global__ __launch_bounds__(256) void k_gemm_qkv(const u16* __restrict__ A,
                                                  const u16* __restrict__ Bt,
                                                  u16* __restrict__ qk,
                                                  u16* __restrict__ vT) {
  __shared__ u16 As[8192];
  __shared__ u16 Bs[8192];
  int wg = (blockIdx.x & 7) * 120 + (blockIdx.x >> 3);
  int by = wg / 12, bx = wg - by * 12;
  int row0 = by * 128, col0 = bx * 128;
  int tid = threadIdx.x;
  int wave = tid >> 6, lane = tid & 63;
  int wm = wave >> 1, wn = wave & 1;
  int l15 = lane & 15, l16 = lane >> 4;
  f32x4 acc[4][4];
  #pragma unroll
  for (int i = 0; i < 4; i++)
    #pragma unroll
    for (int j = 0; j < 4; j++) acc[i][j] = (f32x4){0.f, 0.f, 0.f, 0.f};

  for (int kt = 0; kt < 8; kt++) {
    const u16* Ab = A  + ((size_t)(row0 >> 7) * 8 + kt) * 8192;
    const u16* Bb = Bt + ((size_t)(col0 >> 7) * 8 + kt) * 8192;
    #pragma unroll
    for (int i = 0; i < 4; i++) {
      int off = ((wave * 2 + (i >> 1)) * 128 + (i & 1) * 64) * 8;
      gload16(Ab + off + (size_t)lane * 8, (char*)As + off * 2);
      gload16(Bb + off + (size_t)lane * 8, (char*)Bs + off * 2);
    }
    __syncthreads();
    #pragma unroll
    for (int h = 0; h < 2; h++) {
      bf16x8 af[4], bfr[4];
      #pragma unroll
      for (int mf = 0; mf < 4; mf++)
        af[mf] = *(const bf16x8*)&As[((h * 4 + l16) * 128 + wm * 64 + mf * 16 + l15) * 8];
      #pragma unroll
      for (int nf = 0; nf < 4; nf++)
        bfr[nf] = *(const bf16x8*)&Bs[((h * 4 + l16) * 128 + wn * 64 + nf * 16 + l15) * 8];
      #pragma unroll
      for (int mf = 0; mf < 4; mf++)
        #pragma unroll
        for (int nf = 0; nf < 4; nf++)
          acc[mf][nf] = __builtin_amdgcn_mfma_f32_16x16x32_bf16(af[mf], bfr[nf], acc[mf][nf], 0, 0, 0);
    }
    __syncthreads();
  }

  if (bx < 8) {      // q or k: apply RoPE to pairs (d, d+32), d = nf*16+l15, nf in {0,1}
    #pragma unroll
    for (int nf = 0; nf < 2; nf++) {
      int d = nf * 16 + l15;
      float fr = __expf(-0.2878231366242558f * (float)d);    // 10000^(-d/32)
      #pragma unroll
      for (int mf = 0; mf < 4; mf++)
        #pragma unroll
        for (int r = 0; r < 4; r++) {
          int row = row0 + wm * 64 + mf * 16 + l16 * 4 + r;
          int s = row & (kS - 1);
          float sn, cs;
          __sincosf((float)s * fr, &sn, &cs);
          float x1 = acc[mf][nf][r], x2 = acc[mf][nf + 2][r];
          size_t base = (size_t)row * kQK + col0 + wn * 64 + nf * 16 + l15;
          qk[base]      = bf1(x1 * cs - x2 * sn);
          qk[base + 32] = bf1(x1 * sn + x2 * cs);
        }
    }
  } else {           // v: store transposed per head: vT[(n*8+h)*64 + d][s]
    int n = row0 >> 9;
    #pragma unroll
    for (int mf = 0; mf < 4; mf++) {
      int s0 = (row0 & (kS - 1)) + wm * 64 + mf * 16 + l16 * 4;
      #pragma unroll
      for (int nf = 0; nf < 4; nf++) {
        int v = (bx - 8) * 128 + wn * 64 + nf * 16 + l15;   // 0..511
        int hh = v >> 6, d = v & 63;
        uint2 ow;
        ow.x = pk2(acc[mf][nf][0], acc[mf][nf][1]);
        ow.y = pk2(acc[mf][nf][2], acc[mf][nf][3]);
        *(uint2*)&vT[(size_t)((n * kNH + hh) * kHD + d) * kS + s0] = ow;
      }
    }
  }
}

// ---------------- 128x64-tile GEMM (tiled A,B), C fp32 += A@B ----------------
__global__ __launch_bounds__(256) void k_gemm_n64(const u16* __restrict__ A,
                                                  const u16* __restrict__ Bt,
                                                  float* __restrict__ C,
                                                  int Kt, int N) {
  __shared__ u16 As[8192];
  __shared__ u16 Bs[4096];
  int nwg = gridDim.x;
  int wg = (blockIdx.x & 7) * (nwg >> 3) + (blockIdx.x >> 3);
  int by = wg >> 3, bx = wg & 7;
  int row0 = by * 128, col0 = bx * 64;
  int p = col0 >> 7, half = (col0 >> 6) & 1;
  int tid = threadIdx.x;
  int wave = tid >> 6, lane = tid & 63;
  int l15 = lane & 15, l16 = lane >> 4;
  f32x4 acc[2][4];
  #pragma unroll
  for (int i = 0; i < 2; i++)
    #pragma unroll
    for (int j = 0; j < 4; j++) acc[i][j] = (f32x4){0.f, 0.f, 0.f, 0.f};

  for (int kt = 0; kt < Kt; kt++) {
    const u16* Ab = A  + ((size_t)(row0 >> 7) * Kt + kt) * 8192;
    const u16* Bb = Bt + ((size_t)p * Kt + kt) * 8192;
    #pragma unroll
    for (int i = 0; i < 4; i++) {
      int off = ((wave * 2 + (i >> 1)) * 128 + (i & 1) * 64) * 8;
      gload16(Ab + off + (size_t)lane * 8, (char*)As + off * 2);
    }
    #pragma unroll
    for (int sl = 0; sl < 2; sl++) {
      int ch = wave * 2 + sl;
      gload16(Bb + (ch * 128 + half * 64) * 8 + (size_t)lane * 8,
              (char*)Bs + (ch * 64) * 16);
    }
    __syncthreads();
    #pragma unroll
    for (int h = 0; h < 2; h++) {
      bf16x8 af[2], bfr[4];
      #pragma unroll
      for (int mf = 0; mf < 2; mf++)
        af[mf] = *(const bf16x8*)&As[((h * 4 + l16) * 128 + wave * 32 + mf * 16 + l15) * 8];
      #pragma unroll
      for (int nf = 0; nf < 4; nf++)
        bfr[nf] = *(const bf16x8*)&Bs[((h * 4 + l16) * 64 + nf * 16 + l15) * 8];
      #pragma unroll
      for (int mf = 0; mf < 2; mf++)
        #pragma unroll
        for (int nf = 0; nf < 4; nf++)
          acc[mf][nf] = __builtin_amdgcn_mfma_f32_16x16x32_bf16(af[mf], bfr[nf], acc[mf][nf], 0, 0, 0);
    }
    __syncthreads();
  }
  #pragma unroll
  for (int mf = 0; mf < 2; mf++)
    #pragma unroll
    for (int nf = 0; nf < 4; nf++)
      #pragma unroll
      for (int r = 0; r < 4; r++) {
        int row = row0 + wave * 32 + mf * 16 + l16 * 4 + r;
        int col = col0 + nf * 16 + l15;
        C[(size_t)row * N + col] += acc[mf][nf][r];
      }
}

// ---------------- FFN dual GEMM (tiled A,B1,B3): act(tiled,Kt=22) = silu(A@W1)*(A@W3) ----------------
__global__ __launch_bounds__(256) void k_ffn13_bf16(const u16* __restrict__ A,
                                                    const u16* __restrict__ W1t,
                                                    const u16* __restrict__ W3t,
                                                    u16* __restrict__ act) {
  __shared__ u16 As[8192];
  __shared__ u16 B1[8192];
  __shared__ u16 B2[8192];
  int wg = (blockIdx.x & 7) * 110 + (blockIdx.x >> 3);
  int by = wg / 11, bx = wg - by * 11;
  int row0 = by * 128, col0 = bx * 128;
  int tid = threadIdx.x;
  int wave = tid >> 6, lane = tid & 63;
  int wm = wave >> 1, wn = wave & 1;
  int l15 = lane & 15, l16 = lane >> 4;
  f32x4 acc1[4][4], acc2[4][4];
  #pragma unroll
  for (int i = 0; i < 4; i++)
    #pragma unroll
    for (int j = 0; j < 4; j++) {
      acc1[i][j] = (f32x4){0.f, 0.f, 0.f, 0.f};
      acc2[i][j] = (f32x4){0.f, 0.f, 0.f, 0.f};
    }

  for (int kt = 0; kt < 8; kt++) {
    const u16* Ab  = A   + ((size_t)(row0 >> 7) * 8 + kt) * 8192;
    const u16* B1b = W1t + ((size_t)(col0 >> 7) * 8 + kt) * 8192;
    const u16* B3b = W3t + ((size_t)(col0 >> 7) * 8 + kt) * 8192;
    #pragma unroll
    for (int i = 0; i < 4; i++) {
      int off = ((wave * 2 + (i >> 1)) * 128 + (i & 1) * 64) * 8;
      gload16(Ab  + off + (size_t)lane * 8, (char*)As + off * 2);
      gload16(B1b + off + (size_t)lane * 8, (char*)B1 + off * 2);
      gload16(B3b + off + (size_t)lane * 8, (char*)B2 + off * 2);
    }
    __syncthreads();
    #pragma unroll
    for (int h = 0; h < 2; h++) {
      bf16x8 af[4], b1f[4], b2f[4];
      #pragma unroll
      for (int mf = 0; mf < 4; mf++)
        af[mf] = *(const bf16x8*)&As[((h * 4 + l16) * 128 + wm * 64 + mf * 16 + l15) * 8];
      #pragma unroll
      for (int nf = 0; nf < 4; nf++) {
        b1f[nf] = *(const bf16x8*)&B1[((h * 4 + l16) * 128 + wn * 64 + nf * 16 + l15) * 8];
        b2f[nf] = *(const bf16x8*)&B2[((h * 4 + l16) * 128 + wn * 64 + nf * 16 + l15) * 8];
      }
      #pragma unroll
      for (int mf = 0; mf < 4; mf++)
        #pragma unroll
        for (int nf = 0; nf < 4; nf++) {
          acc1[mf][nf] = __builtin_amdgcn_mfma_f32_16x16x32_bf16(af[mf], b1f[nf], acc1[mf][nf], 0, 0, 0);
          acc2[mf][nf] = __builtin_amdgcn_mfma_f32_16x16x32_bf16(af[mf], b2f[nf], acc2[mf][nf], 0, 0, 0);
        }
    }
    __syncthreads();
  }
  #pragma unroll
  for (int mf = 0; mf < 4; mf++)
    #pragma unroll
    for (int nf = 0; nf < 4; nf++)
      #pragma unroll
      for (int r = 0; r < 4; r++) {
        int row = row0 + wm * 64 + mf * 16 + l16 * 4 + r;
        int col = col0 + wn * 64 + nf * 16 + l15;
        float aa = acc1[mf][nf][r];
        float sg = 1.f / (1.f + __expf(-aa));
        act[tix(22, row, col)] = bf1(aa * sg * acc2[mf][nf][r]);
      }
}

// ---------------- MFMA flash attention (QBLK=64, qk + vT inputs, TILED out) ----------------
__global__ __launch_bounds__(256) void k_attn_mfma(const u16* __restrict__ qk,
                                                   const u16* __restrict__ vT,
                                                   u16* __restrict__ o) {
  int qt = blockIdx.x;
  int nh = blockIdx.y;
  int hh = nh & (kNH - 1), n = nh >> 3;
  int tid = threadIdx.x;
  int wq = tid >> 6, lane = tid & 63;
  int l15 = lane & 15, l16 = lane >> 4;
  __shared__ u16 Ks[64 * kStr];        // [kv][hd]
  __shared__ u16 Vt[64 * kStr];        // [hd][kv]
  __shared__ u16 Ps[4][16 * kStr];     // per-wave P [q][kv]
  int q0 = qt * 64;
  int qrow = q0 + wq * 16 + l15;

  bf16x8 qf[2];
  {
    const u16* qg = qk + (size_t)(n * kS + qrow) * kQK + hh * kHD;
    qf[0] = *(const bf16x8*)(qg + l16 * 8);
    qf[1] = *(const bf16x8*)(qg + 32 + l16 * 8);
  }

  f32x4 oacc[4];
  #pragma unroll
  for (int i = 0; i < 4; i++) oacc[i] = (f32x4){0.f, 0.f, 0.f, 0.f};
  float m_run = -1e30f, l_run = 0.f;

  int skv = tid & 63, sd0 = (tid >> 6) * 16;
  const u16* vTh = vT + (size_t)((n * kNH + hh) * kHD) * kS;

  for (int jt = 0; jt <= qt; jt++) {
    int j0 = jt * 64;
    __syncthreads();
    {
      size_t gb = (size_t)(n * kS + j0 + skv) * kQK + 512 + hh * kHD + sd0;
      const u16* kg = qk + gb;
      *(uint4*)&Ks[skv * kStr + sd0]     = *(const uint4*)kg;
      *(uint4*)&Ks[skv * kStr + sd0 + 8] = *(const uint4*)(kg + 8);
      const u16* vg = vTh + (size_t)skv * kS + j0 + sd0;
      *(uint4*)&Vt[skv * kStr + sd0]     = *(const uint4*)vg;
      *(uint4*)&Vt[skv * kStr + sd0 + 8] = *(const uint4*)(vg + 8);
    }
    __syncthreads();

    f32x4 st[4];
    #pragma unroll
    for (int kt = 0; kt < 4; kt++) {
      bf16x8 ka0 = *(const bf16x8*)&Ks[(kt * 16 + l15) * kStr + l16 * 8];
      bf16x8 ka1 = *(const bf16x8*)&Ks[(kt * 16 + l15) * kStr + 32 + l16 * 8];
      f32x4 c = (f32x4){0.f, 0.f, 0.f, 0.f};
      c = __builtin_amdgcn_mfma_f32_16x16x32_bf16(ka0, qf[0], c, 0, 0, 0);
      c = __builtin_amdgcn_mfma_f32_16x16x32_bf16(ka1, qf[1], c, 0, 0, 0);
      st[kt] = c;
    }

    if (jt == qt) {                        // mask only needed on the diagonal tile
      #pragma unroll
      for (int kt = 0; kt < 4; kt++)
        #pragma unroll
        for (int r = 0; r < 4; r++)
          if (j0 + kt * 16 + l16 * 4 + r > qrow) st[kt][r] = -1e30f;
    }
    float mx = m_run;
    #pragma unroll
    for (int kt = 0; kt < 4; kt++)
      #pragma unroll
      for (int r = 0; r < 4; r++) mx = fmaxf(mx, st[kt][r]);
    mx = fmaxf(mx, __shfl_xor(mx, 16));
    mx = fmaxf(mx, __shfl_xor(mx, 32));
    float sc = __expf(m_run - mx);
    float p[4][4];
    float rs = 0.f;
    #pragma unroll
    for (int kt = 0; kt < 4; kt++)
      #pragma unroll
      for (int r = 0; r < 4; r++) { p[kt][r] = __expf(st[kt][r] - mx); rs += p[kt][r]; }
    rs += __shfl_xor(rs, 16);
    rs += __shfl_xor(rs, 32);
    l_run = l_run * sc + rs;
    m_run = mx;
    #pragma unroll
    for (int dt = 0; dt < 4; dt++)
      #pragma unroll
      for (int r = 0; r < 4; r++) oacc[dt][r] *= sc;

    #pragma unroll
    for (int kt = 0; kt < 4; kt++) {
      uint2 w2;
      w2.x = pk2(p[kt][0], p[kt][1]);
      w2.y = pk2(p[kt][2], p[kt][3]);
      *(uint2*)&Ps[wq][l15 * kStr + kt * 16 + l16 * 4] = w2;
    }
    asm volatile("s_waitcnt lgkmcnt(0)" ::: "memory");
    __builtin_amdgcn_sched_barrier(0);

    bf16x8 pf0 = *(const bf16x8*)&Ps[wq][l15 * kStr + l16 * 8];
    bf16x8 pf1 = *(const bf16x8*)&Ps[wq][l15 * kStr + 32 + l16 * 8];
    #pragma unroll
    for (int dt = 0; dt < 4; dt++) {
      bf16x8 va0 = *(const bf16x8*)&Vt[(dt * 16 + l15) * kStr + l16 * 8];
      bf16x8 va1 = *(const bf16x8*)&Vt[(dt * 16 + l15) * kStr + 32 + l16 * 8];
      oacc[dt] = __builtin_amdgcn_mfma_f32_16x16x32_bf16(va0, pf0, oacc[dt], 0, 0, 0);
      oacc[dt] = __builtin_amdgcn_mfma_f32_16x16x32_bf16(va1, pf1, oacc[dt], 0, 0, 0);
    }
  }

  // tiled store: k = hh*64 + dt*16 + l16*4 -> panel (row>>7), ktile hh
  float inv = 1.f / l_run;
  int rowIdx = n * kS + qrow;
  #pragma unroll
  for (int dt = 0; dt < 4; dt++) {
    uint2 ow;
    ow.x = pk2(oacc[dt][0] * inv, oacc[dt][1] * inv);
    ow.y = pk2(oacc[dt][2] * inv, oacc[dt][3] * inv);
    size_t base = ((size_t)(rowIdx >> 7) * 8 + hh) * 8192 +
                  (size_t)(((dt * 2 + ((l16 >> 1) & 1)) * 128 + (rowIdx & 127)) * 8 + (l16 & 1) * 4);
    *(uint2*)&o[base] = ow;
  }
}

// ---------------- final rmsnorm + gather: only the 80 scoring rows ----------------
__global__ __launch_bounds__(256) void k_rms_gather(const float* __restrict__ x,
                                                    const float* __restrict__ w,
                                                    u16* __restrict__ hs) {
  int r = blockIdx.x;                       // 0..79
  int n = r >> 2, li = r & 3;
  int row = n * kS + (kT - 1 + li);
  int tid = threadIdx.x;
  const float* xr = x + (size_t)row * kD;
  int i = tid * 2;
  float v0 = xr[i], v1 = xr[i + 1];
  float ss = v0 * v0 + v1 * v1;
  #pragma unroll
  for (int o = 1; o < 64; o <<= 1) ss += __shfl_xor(ss, o);
  __shared__ float wsum[4];
  int lane = tid & 63, wid = tid >> 6;
  if (lane == 0) wsum[wid] = ss;
  __syncthreads();
  float tot = wsum[0] + wsum[1] + wsum[2] + wsum[3];
  float inv = rsqrtf(tot / (float)kD + kEps);
  *(u32*)&hs[(size_t)r * kD + i] = pk2(v0 * inv * w[i], v1 * inv * w[i + 1]);
}

// ---------------- logits partials via MFMA (A bf16 plain, lm fp32 streamed) ----------------
// B staged in slot layout [(k>>3)&3][col 0..255][k&7]: conflict-free writes + b128 reads.
__global__ __launch_bounds__(256) void k_logits_mfma(const u16* __restrict__ hs,
                                                     const float* __restrict__ lm,
                                                     float* __restrict__ part) {
  __shared__ u16 As[80 * kPad];
  __shared__ u16 Bs[4 * 256 * 8];
  int tid = threadIdx.x;
  int wave = tid >> 6, lane = tid & 63;
  int l15 = lane & 15, l16 = lane >> 4;
  int col0 = blockIdx.x * 256;
  f32x4 acc[5][4];
  #pragma unroll
  for (int i = 0; i < 5; i++)
    #pragma unroll
    for (int j = 0; j < 4; j++) acc[i][j] = (f32x4){0.f, 0.f, 0.f, 0.f};

  int arow = tid >> 1, ahalf = tid & 1;
  int bkp = tid >> 4, bf4 = tid & 15;     // k-pair 0..15, col-quad 0..15
  int slot = bkp >> 2, ksub = (2 * bkp) & 7;

  for (int k0 = 0; k0 < kD; k0 += 32) {
    if (tid < 160) {
      const u16* ag = hs + (size_t)arow * kD + k0 + ahalf * 16;
      *(uint4*)&As[arow * kPad + ahalf * 16]     = *(const uint4*)ag;
      *(uint4*)&As[arow * kPad + ahalf * 16 + 8] = *(const uint4*)(ag + 8);
    }
    #pragma unroll
    for (int t = 0; t < 4; t++) {
      int colq = bf4 + 16 * t;
      const float* bg = lm + (size_t)(k0 + 2 * bkp) * kV + col0 + colq * 4;
      float4 lo = *(const float4*)bg;
      float4 hi = *(const float4*)(bg + kV);
      *(u32*)&Bs[(slot * 256 + colq * 4 + 0) * 8 + ksub] = pk2(lo.x, hi.x);
      *(u32*)&Bs[(slot * 256 + colq * 4 + 1) * 8 + ksub] = pk2(lo.y, hi.y);
      *(u32*)&Bs[(slot * 256 + colq * 4 + 2) * 8 + ksub] = pk2(lo.z, hi.z);
      *(u32*)&Bs[(slot * 256 + colq * 4 + 3) * 8 + ksub] = pk2(lo.w, hi.w);
    }
    __syncthreads();
    bf16x8 af[5], bfr[4];
    #pragma unroll
    for (int mf = 0; mf < 5; mf++)
      af[mf] = *(const bf16x8*)&As[(mf * 16 + l15) * kPad + l16 * 8];
    #pragma unroll
    for (int nf = 0; nf < 4; nf++)
      bfr[nf] = *(const bf16x8*)&Bs[(l16 * 256 + wave * 64 + nf * 16 + l15) * 8];
    #pragma unroll
    for (int mf = 0; mf < 5; mf++)
      #pragma unroll
      for (int nf = 0; nf < 4; nf++)
        acc[mf][nf] = __builtin_amdgcn_mfma_f32_16x16x32_bf16(af[mf], bfr[nf], acc[mf][nf], 0, 0, 0);
    __syncthreads();
  }

  int chunk = blockIdx.x * 4 + wave;
  #pragma unroll
  for (int mf = 0; mf < 5; mf++)
    #pragma unroll
    for (int r = 0; r < 4; r++) {
      float mx = fmaxf(fmaxf(acc[mf][0][r], acc[mf][1][r]),
                       fmaxf(acc[mf][2][r], acc[mf][3][r]));
      #pragma unroll
      for (int off = 1; off < 16; off <<= 1) mx = fmaxf(mx, __shfl_xor(mx, off));
      float se = expf(acc[mf][0][r] - mx) + expf(acc[mf][1][r] - mx) +
                 expf(acc[mf][2][r] - mx) + expf(acc[mf][3][r] - mx);
      #pragma unroll
      for (int off = 1; off < 16; off <<= 1) se += __shfl_xor(se, off);
      if (l15 == 0) {
        int row = mf * 16 + l16 * 4 + r;
        size_t pi = ((size_t)row * kNChunk + chunk) * 2;
        part[pi] = mx; part[pi + 1] = se;
      }
    }
}

// ---------------- final: label logits + logsumexp combine + output ----------------
__global__ __launch_bounds__(64) void k_final(const float* __restrict__ part,
                                              const u16* __restrict__ hs,
                                              const float* __restrict__ lm,
                                              const int* __restrict__ label_ids,
                                              float* __restrict__ out) {
  int n = blockIdx.x;
  int lab = n / kB, b = n - lab * kB;
  int lane = threadIdx.x;
  float res = 0.f;
  for (int li = 0; li < kLBL; li++) {
    int r = n * kLBL + li;
    int tok = label_ids[lab * kLBL + li];
    float dv = 0.f;
    for (int d2 = lane; d2 < kD; d2 += 64)
      dv += bf2f(hs[(size_t)r * kD + d2]) * lm[(size_t)d2 * kV + tok];
    #pragma unroll
    for (int o2 = 1; o2 < 64; o2 <<= 1) dv += __shfl_xor(dv, o2);
    const float* pr = part + (size_t)r * kNChunk * 2;
    float mx = -1e30f;
    for (int c = lane; c < kNChunk; c += 64) mx = fmaxf(mx, pr[c * 2]);
    #pragma unroll
    for (int o2 = 1; o2 < 64; o2 <<= 1) mx = fmaxf(mx, __shfl_xor(mx, o2));
    float sum = 0.f;
    for (int c = lane; c < kNChunk; c += 64) sum += pr[c * 2 + 1] * expf(pr[c * 2] - mx);
    #pragma unroll
    for (int o2 = 1; o2 < 64; o2 <<= 1) sum += __shfl_xor(sum, o2);
    res += dv - (mx + logf(sum));
  }
  if (lane == 0) out[b * kNLAB + lab] = res;
}

extern "C" void kernel_launch(void* const* d_in, const int* in_sizes, int n_in,
                              void* d_out, int out_size, void* d_ws, size_t ws_size,
                              hipStream_t stream) {
  const int*   input_ids    = (const int*)d_in[0];
  const int*   label_ids    = (const int*)d_in[1];
  const float* emb          = (const float*)d_in[2];
  const float* wq           = (const float*)d_in[3];
  const float* wk           = (const float*)d_in[4];
  const float* wv           = (const float*)d_in[5];
  const float* wo           = (const float*)d_in[6];
  const float* w1           = (const float*)d_in[7];
  const float* w2           = (const float*)d_in[8];
  const float* w3           = (const float*)d_in[9];
  const float* attn_norm_w  = (const float*)d_in[10];
  const float* ffn_norm_w   = (const float*)d_in[11];
  const float* final_norm_w = (const float*)d_in[12];
  const float* lm_head      = (const float*)d_in[13];
  float* out = (float*)d_out;

  char* ws = (char*)d_ws;
  float* h    = (float*)(ws);                  // 20,971,520 B fp32
  u16*   xn   = (u16*)(ws + 20971520);         // 10,485,760 bf16 (tiled Kt=8)
  u16*   qk   = (u16*)(ws + 31457280);         // 20,971,520 bf16 [kNS][1024] plain
  u16*   vT   = (u16*)(ws + 52428800);         // 10,485,760 bf16 [20*8*64][512]
  u16*   big  = (u16*)(ws + 62914560);         // 28,835,840 (attn-out tiled Kt=8 / ffn act tiled Kt=22)
  u16*   hsb  = (u16*)(ws + 91750400);         // 81,920 plain [80][512]
  float* part = (float*)(ws + 91832320);       // 1,280,000
  u16*   wT   = (u16*)(ws + 93112640);         // 12,845,056 (tiled)

  k_wtrans_all<<<2 * 3136, 256, 0, stream>>>(wq, wk, wv, wo, w1, w3, w2, wT);
  k_embed_rms<<<kNS, 256, 0, stream>>>(input_ids, label_ids, emb, attn_norm_w, h, xn);

  for (int l = 0; l < kNL; l++) {
    u16* base = wT + (size_t)l * kPL;
    if (l > 0)
      k_rmsnorm<<<kNS, 256, 0, stream>>>(h, attn_norm_w + (size_t)l * kD, xn);
    k_gemm_qkv<<<960, 256, 0, stream>>>(xn, base + oWQ, qk, vT);
    dim3 gattn(kS / 64, kNSeq * kNH);
    k_attn_mfma<<<gattn, 256, 0, stream>>>(qk, vT, big);
    k_gemm_n64<<<640, 256, 0, stream>>>(big, base + oWO, h, 8, kD);
    k_rmsnorm<<<kNS, 256, 0, stream>>>(h, ffn_norm_w + (size_t)l * kD, xn);
    k_ffn13_bf16<<<880, 256, 0, stream>>>(xn, base + oW1, base + oW3, big);
    k_gemm_n64<<<640, 256, 0, stream>>>(big, base + oW2, h, 22, kD);
  }

  k_rms_gather<<<kNSeq * kLBL, 256, 0, stream>>>(h, final_norm_w, hsb);
  k_logits_mfma<<<kV / 256, 256, 0, stream>>>(hsb, lm_head, part);
  k_final<<<kNSeq, 64, 0, stream>>>(part, hsb, lm_head, label_ids, out);
}